// Round 10
// baseline (497.112 us; speedup 1.0000x reference)
//
#include <hip/hip_runtime.h>

#define NN 50000
#define NE 250000
#define NSCAN_BLKS ((NN + 255)/256)
#define EDGE_BLKS ((4*NE + 255)/256)
#define NBUCK 4
#define BSZ ((NN + NBUCK - 1)/NBUCK)

typedef __attribute__((ext_vector_type(8))) short bf16x8;
typedef __attribute__((ext_vector_type(4))) float f32x4;

__device__ inline ushort f2bf(float f) {          // RNE float->bf16
  uint u = __float_as_uint(f);
  return (ushort)((u + 0x7fffu + ((u >> 16) & 1u)) >> 16);
}
__device__ inline float bf2f(ushort b) { return __uint_as_float(((uint)b) << 16); }

// ---------------- small utils ----------------
__global__ __launch_bounds__(256) void zero_ints(int* __restrict__ p, int n) {
  int i = blockIdx.x*256 + threadIdx.x;
  if (i < n) p[i] = 0;
}
__global__ __launch_bounds__(256) void zero_floats(float* __restrict__ p, int n) {
  int i = blockIdx.x*256 + threadIdx.x;
  if (i < n) p[i] = 0.f;
}

// ---------------- unified CSR build (dst-keyed, etype-ordered sub-rows) ----------------
__global__ __launch_bounds__(256) void count_kernel(const int* __restrict__ edges, int* __restrict__ counts) {
  int idx = blockIdx.x*256 + threadIdx.x;
  if (idx >= 4*NE) return;
  int t = idx / NE, e = idx - t*NE;
  int dst = edges[(size_t)t*2*NE + NE + e];
  atomicAdd(&counts[t*NN + dst], 1);
}

__global__ __launch_bounds__(256) void sumdeg_kernel(const int* __restrict__ counts, int* __restrict__ totdeg) {
  int v = blockIdx.x*256 + threadIdx.x;
  if (v < NN) totdeg[v] = counts[v] + counts[NN+v] + counts[2*NN+v] + counts[3*NN+v];
}

__global__ __launch_bounds__(256) void scan1_kernel(const int* __restrict__ in, int* __restrict__ out, int* __restrict__ bsum, int n) {
  __shared__ int sd[256];
  int i = blockIdx.x*256 + threadIdx.x;
  int v = (i < n) ? in[i] : 0;
  sd[threadIdx.x] = v;
  __syncthreads();
  for (int off = 1; off < 256; off <<= 1) {
    int add = (threadIdx.x >= off) ? sd[threadIdx.x - off] : 0;
    __syncthreads();
    sd[threadIdx.x] += add;
    __syncthreads();
  }
  if (i < n) out[i] = sd[threadIdx.x] - v;          // exclusive within block
  if (threadIdx.x == 255) bsum[blockIdx.x] = sd[255];
}

__global__ __launch_bounds__(1024) void scan2_kernel(int* __restrict__ bsum, int nb) {
  __shared__ int sd[1024];
  int i = threadIdx.x;
  int v = (i < nb) ? bsum[i] : 0;
  sd[i] = v;
  __syncthreads();
  for (int off = 1; off < 1024; off <<= 1) {
    int add = (i >= off) ? sd[i - off] : 0;
    __syncthreads();
    sd[i] += add;
    __syncthreads();
  }
  if (i < nb) bsum[i] = sd[i] - v;
}

__global__ __launch_bounds__(256) void scan3b_kernel(int* __restrict__ rp, const int* __restrict__ bsum, int n, int total) {
  int i = blockIdx.x*256 + threadIdx.x;
  if (i < n) rp[i] += bsum[blockIdx.x];
  if (i == 0) rp[n] = total;
}

__global__ __launch_bounds__(256) void make_cursor_kernel(const int* __restrict__ rp2, const int* __restrict__ counts,
                                                          int* __restrict__ cursor, int* __restrict__ sub_ptr) {
  int v = blockIdx.x*256 + threadIdx.x;
  if (v >= NN) return;
  int b = rp2[v];
  int s1 = b  + counts[v];
  int s2 = s1 + counts[NN+v];
  int s3 = s2 + counts[2*NN+v];
  cursor[v] = b; cursor[NN+v] = s1; cursor[2*NN+v] = s2; cursor[3*NN+v] = s3;
  sub_ptr[NN+v] = s1; sub_ptr[2*NN+v] = s2; sub_ptr[3*NN+v] = s3;
}

// dst-bucketed scatter: blockIdx-major bucket epochs keep col2/cursor writes in a
// ~1.2 MB window -> L2 line reuse instead of per-store dirty-line writeback.
__global__ __launch_bounds__(256) void scatter_bucketed(const int* __restrict__ edges, int* __restrict__ cursor,
                                                        int* __restrict__ col2) {
  const int b = blockIdx.x / EDGE_BLKS;
  const int idx = (blockIdx.x - b*EDGE_BLKS)*256 + threadIdx.x;
  if (idx >= 4*NE) return;
  const int t = idx / NE, e = idx - t*NE;
  const int dst = edges[(size_t)t*2*NE + NE + e];
  if (dst < b*BSZ || dst >= (b+1)*BSZ) return;
  const int src = edges[(size_t)t*2*NE + e];
  const int pos = atomicAdd(&cursor[t*NN + dst], 1);
  col2[pos] = src;
}

// ---------------- input converts ----------------
__global__ __launch_bounds__(256) void convert_x_kernel(const float* __restrict__ x, ushort* __restrict__ xpad) {
  int i = blockIdx.x*256 + threadIdx.x;     // over NN*64
  if (i >= NN*64) return;
  int k = i & 63, n = i >> 6;
  xpad[i] = (k < 23) ? f2bf(x[n*23 + k]) : (ushort)0;
}

// WB[t][c][k] = bf16(W[t][k][c]), k padded to 64 (c = h*64 + dim)
__global__ __launch_bounds__(256) void convert_wb_kernel(const float* __restrict__ W, ushort* __restrict__ WB, int Kin) {
  int i = blockIdx.x*256 + threadIdx.x;     // over 4*128*64
  if (i >= 4*128*64) return;
  int k = i & 63, c = (i >> 6) & 127, t = i >> 13;
  float w = (k < Kin) ? W[((size_t)t*Kin + k)*128 + c] : 0.f;
  WB[i] = f2bf(w);
}

// wwb[c][k], c=0..15: lr=c>>3, t=(c>>1)&3, h=c&1; val = (W_t[:,h-block] @ a_t,h)[k]
__global__ __launch_bounds__(256) void walwar_kernel(const float* __restrict__ W, const float* __restrict__ al,
                                                     const float* __restrict__ ar, ushort* __restrict__ wwb, int Kin) {
  int i = blockIdx.x*256 + threadIdx.x;     // over 16*64
  if (i >= 16*64) return;
  int c = i >> 6, k = i & 63;
  int lr = c >> 3, t = (c >> 1) & 3, h = c & 1;
  float v = 0.f;
  if (k < Kin) {
    const float* A = (lr ? ar : al) + t*128 + h*64;
    const float* wr = W + ((size_t)t*Kin + k)*128 + h*64;
    for (int d = 0; d < 64; ++d) v += wr[d]*A[d];
  }
  wwb[i] = f2bf(v);
}

// ---------------- elk: el/er = h @ wwb^T via one MFMA n-block ----------------
// Block 256 = 4 waves x 16 nodes = 64 nodes. C cols: 0..7 el (t*2+h), 8..15 er.
__global__ __launch_bounds__(256)
void elk_kernel(const ushort* __restrict__ hbf, const ushort* __restrict__ wwb,
                float* __restrict__ elp, float* __restrict__ erp)
{
  __shared__ ushort BS[16*64];    // 2 KB
  __shared__ float sC[16*66];     // padded stride 66 -> 2-way (free)
  const int tid = threadIdx.x;
  if (tid < 128) ((bf16x8*)BS)[tid] = ((const bf16x8*)wwb)[tid];
  __syncthreads();

  const int wv = tid >> 6, lane = tid & 63;
  const int mrow = lane & 15, kq = lane >> 4;
  const int anode = blockIdx.x*64 + wv*16 + mrow;

  const bf16x8 a0 = *(const bf16x8*)(hbf + (size_t)anode*64 + kq*8);
  const bf16x8 a1 = *(const bf16x8*)(hbf + (size_t)anode*64 + 32 + kq*8);
  const bf16x8 b0 = *(const bf16x8*)(BS + mrow*64 + kq*8);
  const bf16x8 b1 = *(const bf16x8*)(BS + mrow*64 + 32 + kq*8);

  f32x4 acc = (f32x4){0.f,0.f,0.f,0.f};
  acc = __builtin_amdgcn_mfma_f32_16x16x32_bf16(a0, b0, acc, 0, 0, 0);
  acc = __builtin_amdgcn_mfma_f32_16x16x32_bf16(a1, b1, acc, 0, 0, 0);

  #pragma unroll
  for (int r = 0; r < 4; ++r) sC[mrow*66 + wv*16 + kq*4 + r] = acc[r];
  __syncthreads();

  const int t = tid >> 6, n = tid & 63;
  const int node = blockIdx.x*64 + n;
  if (node < NN) {
    float2 e2 = make_float2(sC[(t*2+0)*66 + n], sC[(t*2+1)*66 + n]);
    float2 r2 = make_float2(sC[(8+t*2+0)*66 + n], sC[(8+t*2+1)*66 + n]);
    ((float2*)elp)[(size_t)t*NN + node] = e2;
    ((float2*)erp)[(size_t)t*NN + node] = r2;
  }
}

// ---------------- gather: ONE WAVE PER (node, etype) -> 4x TLP, chains ~deg=5 ----------------
// Block = 1 node, wave t handles etype t and writes agg[(t,v)] directly (no combine).
__global__ __launch_bounds__(256)
void gather_kernel(const ushort* __restrict__ hbf, const float* __restrict__ elp,
                   const float* __restrict__ erp, const int* __restrict__ col2,
                   const int* __restrict__ row_ptr2, const int* __restrict__ sub_ptr,
                   ushort* __restrict__ agg)
{
  const int v = __builtin_amdgcn_readfirstlane(blockIdx.x);
  const int t = threadIdx.x >> 6;               // wave-uniform
  const int lane = threadIdx.x & 63;

  const int lo = __builtin_amdgcn_readfirstlane((t == 0) ? row_ptr2[v] : sub_ptr[t*NN + v]);
  const int hi = __builtin_amdgcn_readfirstlane((t == 3) ? row_ptr2[v+1] : sub_ptr[(t+1)*NN + v]);

  float a0 = 0.f, a1 = 0.f;
  if (lo < hi) {
    const float2 er2 = ((const float2*)erp)[(size_t)t*NN + v];
    float sum0 = 0.f, sum1 = 0.f;
    #pragma unroll 2
    for (int q = lo; q < hi; ++q) {
      const int src = __builtin_amdgcn_readfirstlane(col2[q]);
      const float2 e2 = ((const float2*)elp)[(size_t)t*NN + src];
      float u0 = e2.x + er2.x, u1 = e2.y + er2.y;
      u0 = (u0 > 0.f) ? u0 : 0.2f*u0;             // leaky_relu 0.2
      u1 = (u1 > 0.f) ? u1 : 0.2f*u1;
      const float p0 = __expf(fminf(fmaxf(u0, -60.f), 60.f));
      const float p1 = __expf(fminf(fmaxf(u1, -60.f), 60.f));
      sum0 += p0; sum1 += p1;
      const float xv = bf2f(hbf[(size_t)src*64 + lane]);
      a0 += p0*xv; a1 += p1*xv;
    }
    a0 *= __builtin_amdgcn_rcpf(sum0);
    a1 *= __builtin_amdgcn_rcpf(sum1);
  }
  const size_t base = ((size_t)t*NN + v)*128;
  agg[base + lane]      = f2bf(a0);               // head0
  agg[base + 64 + lane] = f2bf(a1);               // head1
}

// ---------------- transform: h' = post(0.25*sum_t(agg_t @ W_t) + bmean) ----------------
// Block 256 = 4 waves x 16 nodes; N=128 (8 n-blocks: 0-3 head0, 4-7 head1); K=64.
// W staged in TWO 32KB stages (etypes {0,1} then {2,3}) -> 4 blocks/CU.
__global__ __launch_bounds__(256)
void transform_kernel(const ushort* __restrict__ agg, const ushort* __restrict__ WB,
                      const float* __restrict__ ball, ushort* __restrict__ hout, int post)
{
  __shared__ ushort WT[2*128*64];   // 32 KB, swizzled
  __shared__ float sb[128];
  const int tid = threadIdx.x;
  if (tid < 128) sb[tid] = 0.25f*(ball[tid] + ball[128+tid] + ball[256+tid] + ball[384+tid]);

  const int wv = tid >> 6, lane = tid & 63;
  const int mrow = lane & 15, kq = lane >> 4;
  const int node0 = blockIdx.x*64;
  const int anode = node0 + wv*16 + mrow;

  f32x4 acc[8];
  #pragma unroll
  for (int nb = 0; nb < 8; ++nb) acc[nb] = (f32x4){0.f,0.f,0.f,0.f};

  for (int tb = 0; tb < 4; tb += 2) {
    __syncthreads();                              // protect WT (and sb on first pass)
    for (int i = tid; i < 2048; i += 256) {       // 16B chunks: rows 0..255 = etypes tb,tb+1
      int row = i >> 3, jj = i & 7;
      bf16x8 val = ((const bf16x8*)WB)[tb*1024 + i];
      *(bf16x8*)((char*)WT + row*128 + ((jj ^ (row & 7))*16)) = val;
    }
    __syncthreads();
    #pragma unroll
    for (int t2 = 0; t2 < 2; ++t2) {
      const int t = tb + t2;
      const ushort* ar_ = agg + ((size_t)t*NN + anode)*128;
      const bf16x8 a00 = *(const bf16x8*)(ar_ + kq*8);        // h0 k0-31
      const bf16x8 a01 = *(const bf16x8*)(ar_ + 32 + kq*8);   // h0 k32-63
      const bf16x8 a10 = *(const bf16x8*)(ar_ + 64 + kq*8);   // h1 k0-31
      const bf16x8 a11 = *(const bf16x8*)(ar_ + 96 + kq*8);   // h1 k32-63
      #pragma unroll
      for (int nb = 0; nb < 8; ++nb) {
        const int row = t2*128 + nb*16 + mrow;
        const bf16x8 b0 = *(const bf16x8*)((const char*)WT + row*128 + ((kq       ^ (row&7))*16));
        const bf16x8 b1 = *(const bf16x8*)((const char*)WT + row*128 + (((4 + kq) ^ (row&7))*16));
        acc[nb] = __builtin_amdgcn_mfma_f32_16x16x32_bf16(nb < 4 ? a00 : a10, b0, acc[nb], 0, 0, 0);
        acc[nb] = __builtin_amdgcn_mfma_f32_16x16x32_bf16(nb < 4 ? a01 : a11, b1, acc[nb], 0, 0, 0);
      }
    }
  }

  const int noder = node0 + wv*16 + kq*4;
  #pragma unroll
  for (int nb = 0; nb < 4; ++nb) {
    const int d = nb*16 + mrow;
    const float bm0 = sb[d], bm1 = sb[64 + d];
    #pragma unroll
    for (int r = 0; r < 4; ++r) {
      if (noder + r < NN) {
        float h0 = 0.25f*acc[nb][r]   + bm0;
        float h1 = 0.25f*acc[nb+4][r] + bm1;
        float o;
        if (post) {
          h0 = fmaxf(h0, 0.f); h1 = fmaxf(h1, 0.f);
          o = 0.5f*(h0 + h1) / fmaxf(sqrtf(h0*h0 + h1*h1), 1e-12f);
        } else {
          o = 0.5f*(h0 + h1);
        }
        hout[(size_t)(noder + r)*64 + d] = f2bf(o);
      }
    }
  }
}

// ---------------- final mean over nodes (bf16 input) ----------------
__global__ __launch_bounds__(256) void reduce_nodes(const ushort* __restrict__ hn, float* __restrict__ accum) {
  __shared__ float sd[256];
  int d = threadIdx.x & 63, rg = threadIdx.x >> 6;
  float s = 0.f;
  for (int r = blockIdx.x*4 + rg; r < NN; r += gridDim.x*4) s += bf2f(hn[(size_t)r*64 + d]);
  sd[threadIdx.x] = s;
  __syncthreads();
  if (threadIdx.x < 64) {
    s = sd[threadIdx.x] + sd[threadIdx.x+64] + sd[threadIdx.x+128] + sd[threadIdx.x+192];
    atomicAdd(&accum[threadIdx.x], s);
  }
}
__global__ __launch_bounds__(64) void final_out_kernel(const float* __restrict__ accum, float* __restrict__ out) {
  int d = threadIdx.x;
  if (d < 64) out[d] = accum[d] * (1.0f/NN);
}

// ---------------- launch ----------------
extern "C" void kernel_launch(void* const* d_in, const int* in_sizes, int n_in,
                              void* d_out, int out_size, void* d_ws, size_t ws_size,
                              hipStream_t stream) {
  const float* x     = (const float*)d_in[0];
  const int*   edges = (const int*)d_in[1];
  const float* W[3]  = {(const float*)d_in[2], (const float*)d_in[6], (const float*)d_in[10]};
  const float* al[3] = {(const float*)d_in[3], (const float*)d_in[7], (const float*)d_in[11]};
  const float* ar[3] = {(const float*)d_in[4], (const float*)d_in[8], (const float*)d_in[12]};
  const float* b[3]  = {(const float*)d_in[5], (const float*)d_in[9], (const float*)d_in[13]};

  char* ws = (char*)d_ws;
  auto up = [](size_t x_) { return (x_ + 255) & ~(size_t)255; };

  const size_t szAgg  = ((size_t)4*NN + 64)*128*sizeof(ushort);  // 51.2 MB (+pad rows)
  const size_t szElp  = (size_t)4*NN*2*sizeof(float);            // 1.6 MB each
  const size_t szHB   = (size_t)(NN+64)*64*sizeof(ushort);       // 6.4 MB each
  const size_t szWB   = (size_t)4*128*64*sizeof(ushort);         // 64 KB
  const size_t szWWB  = (size_t)16*64*sizeof(ushort);            // 2 KB
  const size_t szCol  = (size_t)4*NE*sizeof(int);                // 4 MB
  const size_t szI4   = (size_t)4*NN*sizeof(int);
  const size_t szI1   = (size_t)(NN+1)*sizeof(int);

  size_t o = 0;
  ushort* agg    = (ushort*)(ws + o); o += up(szAgg);
  float*  elp    = (float*)(ws + o);  o += up(szElp);
  float*  erp    = (float*)(ws + o);  o += up(szElp);
  ushort* xpad   = (ushort*)(ws + o); o += up(szHB);
  ushort* hbuf   = (ushort*)(ws + o); o += up(szHB);
  ushort* WB     = (ushort*)(ws + o); o += up(szWB);
  ushort* wwb    = (ushort*)(ws + o); o += up(szWWB);
  float*  accum  = (float*)(ws + o);  o += up(256);
  int*    col2   = (int*)(ws + o);    o += up(szCol);
  int* row_ptr2  = (int*)(ws + o);    o += up(szI1);
  int* totdeg    = (int*)(ws + o);    o += up(szI1);
  int* cursor    = (int*)(ws + o);    o += up(szI4);
  int* counts    = (int*)(ws + o);    o += up(szI4);
  int* sub_ptr   = (int*)(ws + o);    o += up(szI4);
  int* bsum      = (int*)(ws + o);    o += up(4096);

  // ---- unified CSR build (once; shared by all layers) ----
  zero_ints<<<(4*NN + 255)/256, 256, 0, stream>>>(counts, 4*NN);
  count_kernel<<<EDGE_BLKS, 256, 0, stream>>>(edges, counts);
  sumdeg_kernel<<<NSCAN_BLKS, 256, 0, stream>>>(counts, totdeg);
  scan1_kernel<<<NSCAN_BLKS, 256, 0, stream>>>(totdeg, row_ptr2, bsum, NN);
  scan2_kernel<<<1, 1024, 0, stream>>>(bsum, NSCAN_BLKS);
  scan3b_kernel<<<NSCAN_BLKS, 256, 0, stream>>>(row_ptr2, bsum, NN, 4*NE);
  make_cursor_kernel<<<NSCAN_BLKS, 256, 0, stream>>>(row_ptr2, counts, cursor, sub_ptr);
  scatter_bucketed<<<NBUCK*EDGE_BLKS, 256, 0, stream>>>(edges, cursor, col2);

  convert_x_kernel<<<(NN*64 + 255)/256, 256, 0, stream>>>(x, xpad);

  const int gemmGX = (NN + 63)/64;   // 782

  for (int l = 0; l < 3; ++l) {
    const ushort* hin = (l == 0) ? xpad : hbuf;
    const int Kin = (l == 0) ? 23 : 64;
    convert_wb_kernel<<<(4*128*64 + 255)/256, 256, 0, stream>>>(W[l], WB, Kin);
    walwar_kernel<<<(16*64 + 255)/256, 256, 0, stream>>>(W[l], al[l], ar[l], wwb, Kin);
    elk_kernel<<<gemmGX, 256, 0, stream>>>(hin, wwb, elp, erp);
    gather_kernel<<<NN, 256, 0, stream>>>(hin, elp, erp, col2, row_ptr2, sub_ptr, agg);
    transform_kernel<<<gemmGX, 256, 0, stream>>>(agg, WB, b[l], hbuf, (l < 2) ? 1 : 0);
  }

  zero_floats<<<1, 64, 0, stream>>>(accum, 64);
  reduce_nodes<<<256, 256, 0, stream>>>(hbuf, accum);
  final_out_kernel<<<1, 64, 0, stream>>>(accum, (float*)d_out);
}

// Round 11
// 447.187 us; speedup vs baseline: 1.1116x; 1.1116x over previous
//
#include <hip/hip_runtime.h>

#define NN 50000
#define NE 250000
#define NSCAN_BLKS ((NN + 255)/256)
#define EDGE_BLKS ((4*NE + 255)/256)
#define NBUCK 4
#define BSZ ((NN + NBUCK - 1)/NBUCK)

typedef __attribute__((ext_vector_type(8))) short bf16x8;
typedef __attribute__((ext_vector_type(4))) float f32x4;

__device__ inline ushort f2bf(float f) {          // RNE float->bf16
  uint u = __float_as_uint(f);
  return (ushort)((u + 0x7fffu + ((u >> 16) & 1u)) >> 16);
}
__device__ inline float bf2f(ushort b) { return __uint_as_float(((uint)b) << 16); }

// ---------------- small utils ----------------
__global__ __launch_bounds__(256) void zero_ints(int* __restrict__ p, int n) {
  int i = blockIdx.x*256 + threadIdx.x;
  if (i < n) p[i] = 0;
}
__global__ __launch_bounds__(256) void zero_floats(float* __restrict__ p, int n) {
  int i = blockIdx.x*256 + threadIdx.x;
  if (i < n) p[i] = 0.f;
}

// ---------------- unified CSR build (dst-keyed, etype-ordered sub-rows) ----------------
__global__ __launch_bounds__(256) void count_kernel(const int* __restrict__ edges, int* __restrict__ counts) {
  int idx = blockIdx.x*256 + threadIdx.x;
  if (idx >= 4*NE) return;
  int t = idx / NE, e = idx - t*NE;
  int dst = edges[(size_t)t*2*NE + NE + e];
  atomicAdd(&counts[t*NN + dst], 1);
}

__global__ __launch_bounds__(256) void sumdeg_kernel(const int* __restrict__ counts, int* __restrict__ totdeg) {
  int v = blockIdx.x*256 + threadIdx.x;
  if (v < NN) totdeg[v] = counts[v] + counts[NN+v] + counts[2*NN+v] + counts[3*NN+v];
}

__global__ __launch_bounds__(256) void scan1_kernel(const int* __restrict__ in, int* __restrict__ out, int* __restrict__ bsum, int n) {
  __shared__ int sd[256];
  int i = blockIdx.x*256 + threadIdx.x;
  int v = (i < n) ? in[i] : 0;
  sd[threadIdx.x] = v;
  __syncthreads();
  for (int off = 1; off < 256; off <<= 1) {
    int add = (threadIdx.x >= off) ? sd[threadIdx.x - off] : 0;
    __syncthreads();
    sd[threadIdx.x] += add;
    __syncthreads();
  }
  if (i < n) out[i] = sd[threadIdx.x] - v;          // exclusive within block
  if (threadIdx.x == 255) bsum[blockIdx.x] = sd[255];
}

__global__ __launch_bounds__(1024) void scan2_kernel(int* __restrict__ bsum, int nb) {
  __shared__ int sd[1024];
  int i = threadIdx.x;
  int v = (i < nb) ? bsum[i] : 0;
  sd[i] = v;
  __syncthreads();
  for (int off = 1; off < 1024; off <<= 1) {
    int add = (i >= off) ? sd[i - off] : 0;
    __syncthreads();
    sd[i] += add;
    __syncthreads();
  }
  if (i < nb) bsum[i] = sd[i] - v;
}

__global__ __launch_bounds__(256) void scan3b_kernel(int* __restrict__ rp, const int* __restrict__ bsum, int n, int total) {
  int i = blockIdx.x*256 + threadIdx.x;
  if (i < n) rp[i] += bsum[blockIdx.x];
  if (i == 0) rp[n] = total;
}

__global__ __launch_bounds__(256) void make_cursor_kernel(const int* __restrict__ rp2, const int* __restrict__ counts,
                                                          int* __restrict__ cursor, int* __restrict__ sub_ptr) {
  int v = blockIdx.x*256 + threadIdx.x;
  if (v >= NN) return;
  int b = rp2[v];
  int s1 = b  + counts[v];
  int s2 = s1 + counts[NN+v];
  int s3 = s2 + counts[2*NN+v];
  cursor[v] = b; cursor[NN+v] = s1; cursor[2*NN+v] = s2; cursor[3*NN+v] = s3;
  sub_ptr[NN+v] = s1; sub_ptr[2*NN+v] = s2; sub_ptr[3*NN+v] = s3;
}

// dst-bucketed scatter: bucket epochs keep col2/cursor writes in a ~1.2 MB window.
__global__ __launch_bounds__(256) void scatter_bucketed(const int* __restrict__ edges, int* __restrict__ cursor,
                                                        int* __restrict__ col2) {
  const int b = blockIdx.x / EDGE_BLKS;
  const int idx = (blockIdx.x - b*EDGE_BLKS)*256 + threadIdx.x;
  if (idx >= 4*NE) return;
  const int t = idx / NE, e = idx - t*NE;
  const int dst = edges[(size_t)t*2*NE + NE + e];
  if (dst < b*BSZ || dst >= (b+1)*BSZ) return;
  const int src = edges[(size_t)t*2*NE + e];
  const int pos = atomicAdd(&cursor[t*NN + dst], 1);
  col2[pos] = src;
}

// ---------------- input converts ----------------
__global__ __launch_bounds__(256) void convert_x_kernel(const float* __restrict__ x, ushort* __restrict__ xpad) {
  int i = blockIdx.x*256 + threadIdx.x;     // over NN*64
  if (i >= NN*64) return;
  int k = i & 63, n = i >> 6;
  xpad[i] = (k < 23) ? f2bf(x[n*23 + k]) : (ushort)0;
}

// WB[t][c][k] = bf16(W[t][k][c]), k padded to 64 (c = h*64 + dim)
__global__ __launch_bounds__(256) void convert_wb_kernel(const float* __restrict__ W, ushort* __restrict__ WB, int Kin) {
  int i = blockIdx.x*256 + threadIdx.x;     // over 4*128*64
  if (i >= 4*128*64) return;
  int k = i & 63, c = (i >> 6) & 127, t = i >> 13;
  float w = (k < Kin) ? W[((size_t)t*Kin + k)*128 + c] : 0.f;
  WB[i] = f2bf(w);
}

// wwb[c][k], c=0..15: lr=c>>3, t=(c>>1)&3, h=c&1; val = (W_t[:,h-block] @ a_t,h)[k]
__global__ __launch_bounds__(256) void walwar_kernel(const float* __restrict__ W, const float* __restrict__ al,
                                                     const float* __restrict__ ar, ushort* __restrict__ wwb, int Kin) {
  int i = blockIdx.x*256 + threadIdx.x;     // over 16*64
  if (i >= 16*64) return;
  int c = i >> 6, k = i & 63;
  int lr = c >> 3, t = (c >> 1) & 3, h = c & 1;
  float v = 0.f;
  if (k < Kin) {
    const float* A = (lr ? ar : al) + t*128 + h*64;
    const float* wr = W + ((size_t)t*Kin + k)*128 + h*64;
    for (int d = 0; d < 64; ++d) v += wr[d]*A[d];
  }
  wwb[i] = f2bf(v);
}

// ---------------- elk: el/er = h @ wwb^T via one MFMA n-block ----------------
__global__ __launch_bounds__(256)
void elk_kernel(const ushort* __restrict__ hbf, const ushort* __restrict__ wwb,
                float* __restrict__ elp, float* __restrict__ erp)
{
  __shared__ ushort BS[16*64];    // 2 KB
  __shared__ float sC[16*66];     // padded stride 66 -> 2-way (free)
  const int tid = threadIdx.x;
  if (tid < 128) ((bf16x8*)BS)[tid] = ((const bf16x8*)wwb)[tid];
  __syncthreads();

  const int wv = tid >> 6, lane = tid & 63;
  const int mrow = lane & 15, kq = lane >> 4;
  const int anode = blockIdx.x*64 + wv*16 + mrow;

  const bf16x8 a0 = *(const bf16x8*)(hbf + (size_t)anode*64 + kq*8);
  const bf16x8 a1 = *(const bf16x8*)(hbf + (size_t)anode*64 + 32 + kq*8);
  const bf16x8 b0 = *(const bf16x8*)(BS + mrow*64 + kq*8);
  const bf16x8 b1 = *(const bf16x8*)(BS + mrow*64 + 32 + kq*8);

  f32x4 acc = (f32x4){0.f,0.f,0.f,0.f};
  acc = __builtin_amdgcn_mfma_f32_16x16x32_bf16(a0, b0, acc, 0, 0, 0);
  acc = __builtin_amdgcn_mfma_f32_16x16x32_bf16(a1, b1, acc, 0, 0, 0);

  #pragma unroll
  for (int r = 0; r < 4; ++r) sC[mrow*66 + wv*16 + kq*4 + r] = acc[r];
  __syncthreads();

  const int t = tid >> 6, n = tid & 63;
  const int node = blockIdx.x*64 + n;
  if (node < NN) {
    float2 e2 = make_float2(sC[(t*2+0)*66 + n], sC[(t*2+1)*66 + n]);
    float2 r2 = make_float2(sC[(8+t*2+0)*66 + n], sC[(8+t*2+1)*66 + n]);
    ((float2*)elp)[(size_t)t*NN + node] = e2;
    ((float2*)erp)[(size_t)t*NN + node] = r2;
  }
}

// ---------------- gather: wave per node (R9 structure); NT stores kill agg RFO ----------------
__global__ __launch_bounds__(256)
void gather_kernel(const ushort* __restrict__ hbf, const float* __restrict__ elp,
                   const float* __restrict__ erp, const int* __restrict__ col2,
                   const int* __restrict__ row_ptr2, const int* __restrict__ sub_ptr,
                   ushort* __restrict__ agg)
{
  const int v = __builtin_amdgcn_readfirstlane(blockIdx.x*4 + (threadIdx.x >> 6));
  const int lane = threadIdx.x & 63;

  const int b0 = row_ptr2[v];
  const int b4 = row_ptr2[v+1];
  const int s1 = sub_ptr[NN+v], s2 = sub_ptr[2*NN+v], s3 = sub_ptr[3*NN+v];
  const int bounds[5] = {b0, s1, s2, s3, b4};

  #pragma unroll
  for (int t = 0; t < 4; ++t) {
    const int lo = bounds[t], hi = bounds[t+1];
    float a0 = 0.f, a1 = 0.f;
    if (lo < hi) {
      const float2 er2 = ((const float2*)erp)[(size_t)t*NN + v];
      float sum0 = 0.f, sum1 = 0.f;
      for (int q = lo; q < hi; ++q) {
        const int src = __builtin_amdgcn_readfirstlane(col2[q]);
        const float2 e2 = ((const float2*)elp)[(size_t)t*NN + src];
        float u0 = e2.x + er2.x, u1 = e2.y + er2.y;
        u0 = (u0 > 0.f) ? u0 : 0.2f*u0;             // leaky_relu 0.2
        u1 = (u1 > 0.f) ? u1 : 0.2f*u1;
        const float p0 = __expf(fminf(u0, 80.f));   // overflow guard only
        const float p1 = __expf(fminf(u1, 80.f));
        sum0 += p0; sum1 += p1;
        const float xv = bf2f(hbf[(size_t)src*64 + lane]);
        a0 += p0*xv; a1 += p1*xv;
      }
      a0 *= __builtin_amdgcn_rcpf(sum0);
      a1 *= __builtin_amdgcn_rcpf(sum1);
    }
    const size_t base = ((size_t)t*NN + v)*128;
    __builtin_nontemporal_store(f2bf(a0), &agg[base + lane]);       // head0
    __builtin_nontemporal_store(f2bf(a1), &agg[base + 64 + lane]);  // head1
  }
}

// ---------------- transform: h' = post(0.25*sum_t(agg_t @ W_t) + bmean) ----------------
// Block 256 = 4 waves x 16 nodes; N=128 (8 n-blocks: 0-3 head0, 4-7 head1); K=64.
// W staged in TWO 32KB stages; agg read via nontemporal loads (stream-once).
__global__ __launch_bounds__(256)
void transform_kernel(const ushort* __restrict__ agg, const ushort* __restrict__ WB,
                      const float* __restrict__ ball, ushort* __restrict__ hout, int post)
{
  __shared__ ushort WT[2*128*64];   // 32 KB, swizzled
  __shared__ float sb[128];
  const int tid = threadIdx.x;
  if (tid < 128) sb[tid] = 0.25f*(ball[tid] + ball[128+tid] + ball[256+tid] + ball[384+tid]);

  const int wv = tid >> 6, lane = tid & 63;
  const int mrow = lane & 15, kq = lane >> 4;
  const int node0 = blockIdx.x*64;
  const int anode = node0 + wv*16 + mrow;

  f32x4 acc[8];
  #pragma unroll
  for (int nb = 0; nb < 8; ++nb) acc[nb] = (f32x4){0.f,0.f,0.f,0.f};

  for (int tb = 0; tb < 4; tb += 2) {
    __syncthreads();                              // protect WT (and sb on first pass)
    for (int i = tid; i < 2048; i += 256) {       // 16B chunks: rows 0..255 = etypes tb,tb+1
      int row = i >> 3, jj = i & 7;
      bf16x8 val = ((const bf16x8*)WB)[tb*1024 + i];
      *(bf16x8*)((char*)WT + row*128 + ((jj ^ (row & 7))*16)) = val;
    }
    __syncthreads();
    #pragma unroll
    for (int t2 = 0; t2 < 2; ++t2) {
      const int t = tb + t2;
      const ushort* ar_ = agg + ((size_t)t*NN + anode)*128;
      const bf16x8 a00 = __builtin_nontemporal_load((const bf16x8*)(ar_ + kq*8));
      const bf16x8 a01 = __builtin_nontemporal_load((const bf16x8*)(ar_ + 32 + kq*8));
      const bf16x8 a10 = __builtin_nontemporal_load((const bf16x8*)(ar_ + 64 + kq*8));
      const bf16x8 a11 = __builtin_nontemporal_load((const bf16x8*)(ar_ + 96 + kq*8));
      #pragma unroll
      for (int nb = 0; nb < 8; ++nb) {
        const int row = t2*128 + nb*16 + mrow;
        const bf16x8 b0 = *(const bf16x8*)((const char*)WT + row*128 + ((kq       ^ (row&7))*16));
        const bf16x8 b1 = *(const bf16x8*)((const char*)WT + row*128 + (((4 + kq) ^ (row&7))*16));
        acc[nb] = __builtin_amdgcn_mfma_f32_16x16x32_bf16(nb < 4 ? a00 : a10, b0, acc[nb], 0, 0, 0);
        acc[nb] = __builtin_amdgcn_mfma_f32_16x16x32_bf16(nb < 4 ? a01 : a11, b1, acc[nb], 0, 0, 0);
      }
    }
  }

  const int noder = node0 + wv*16 + kq*4;
  #pragma unroll
  for (int nb = 0; nb < 4; ++nb) {
    const int d = nb*16 + mrow;
    const float bm0 = sb[d], bm1 = sb[64 + d];
    #pragma unroll
    for (int r = 0; r < 4; ++r) {
      if (noder + r < NN) {
        float h0 = 0.25f*acc[nb][r]   + bm0;
        float h1 = 0.25f*acc[nb+4][r] + bm1;
        float o;
        if (post) {
          h0 = fmaxf(h0, 0.f); h1 = fmaxf(h1, 0.f);
          o = 0.5f*(h0 + h1) / fmaxf(sqrtf(h0*h0 + h1*h1), 1e-12f);
        } else {
          o = 0.5f*(h0 + h1);
        }
        hout[(size_t)(noder + r)*64 + d] = f2bf(o);
      }
    }
  }
}

// ---------------- final mean over nodes (bf16 input) ----------------
__global__ __launch_bounds__(256) void reduce_nodes(const ushort* __restrict__ hn, float* __restrict__ accum) {
  __shared__ float sd[256];
  int d = threadIdx.x & 63, rg = threadIdx.x >> 6;
  float s = 0.f;
  for (int r = blockIdx.x*4 + rg; r < NN; r += gridDim.x*4) s += bf2f(hn[(size_t)r*64 + d]);
  sd[threadIdx.x] = s;
  __syncthreads();
  if (threadIdx.x < 64) {
    s = sd[threadIdx.x] + sd[threadIdx.x+64] + sd[threadIdx.x+128] + sd[threadIdx.x+192];
    atomicAdd(&accum[threadIdx.x], s);
  }
}
__global__ __launch_bounds__(64) void final_out_kernel(const float* __restrict__ accum, float* __restrict__ out) {
  int d = threadIdx.x;
  if (d < 64) out[d] = accum[d] * (1.0f/NN);
}

// ---------------- launch ----------------
extern "C" void kernel_launch(void* const* d_in, const int* in_sizes, int n_in,
                              void* d_out, int out_size, void* d_ws, size_t ws_size,
                              hipStream_t stream) {
  const float* x     = (const float*)d_in[0];
  const int*   edges = (const int*)d_in[1];
  const float* W[3]  = {(const float*)d_in[2], (const float*)d_in[6], (const float*)d_in[10]};
  const float* al[3] = {(const float*)d_in[3], (const float*)d_in[7], (const float*)d_in[11]};
  const float* ar[3] = {(const float*)d_in[4], (const float*)d_in[8], (const float*)d_in[12]};
  const float* b[3]  = {(const float*)d_in[5], (const float*)d_in[9], (const float*)d_in[13]};

  char* ws = (char*)d_ws;
  auto up = [](size_t x_) { return (x_ + 255) & ~(size_t)255; };

  const size_t szAgg  = ((size_t)4*NN + 64)*128*sizeof(ushort);  // 51.2 MB (+pad rows)
  const size_t szElp  = (size_t)4*NN*2*sizeof(float);            // 1.6 MB each
  const size_t szHB   = (size_t)(NN+64)*64*sizeof(ushort);       // 6.4 MB each
  const size_t szWB   = (size_t)4*128*64*sizeof(ushort);         // 64 KB
  const size_t szWWB  = (size_t)16*64*sizeof(ushort);            // 2 KB
  const size_t szCol  = (size_t)4*NE*sizeof(int);                // 4 MB
  const size_t szI4   = (size_t)4*NN*sizeof(int);
  const size_t szI1   = (size_t)(NN+1)*sizeof(int);

  size_t o = 0;
  ushort* agg    = (ushort*)(ws + o); o += up(szAgg);
  float*  elp    = (float*)(ws + o);  o += up(szElp);
  float*  erp    = (float*)(ws + o);  o += up(szElp);
  ushort* xpad   = (ushort*)(ws + o); o += up(szHB);
  ushort* hbuf   = (ushort*)(ws + o); o += up(szHB);
  ushort* WB     = (ushort*)(ws + o); o += up(szWB);
  ushort* wwb    = (ushort*)(ws + o); o += up(szWWB);
  float*  accum  = (float*)(ws + o);  o += up(256);
  int*    col2   = (int*)(ws + o);    o += up(szCol);
  int* row_ptr2  = (int*)(ws + o);    o += up(szI1);
  int* totdeg    = (int*)(ws + o);    o += up(szI1);
  int* cursor    = (int*)(ws + o);    o += up(szI4);
  int* counts    = (int*)(ws + o);    o += up(szI4);
  int* sub_ptr   = (int*)(ws + o);    o += up(szI4);
  int* bsum      = (int*)(ws + o);    o += up(4096);

  // ---- unified CSR build (once; shared by all layers) ----
  zero_ints<<<(4*NN + 255)/256, 256, 0, stream>>>(counts, 4*NN);
  count_kernel<<<EDGE_BLKS, 256, 0, stream>>>(edges, counts);
  sumdeg_kernel<<<NSCAN_BLKS, 256, 0, stream>>>(counts, totdeg);
  scan1_kernel<<<NSCAN_BLKS, 256, 0, stream>>>(totdeg, row_ptr2, bsum, NN);
  scan2_kernel<<<1, 1024, 0, stream>>>(bsum, NSCAN_BLKS);
  scan3b_kernel<<<NSCAN_BLKS, 256, 0, stream>>>(row_ptr2, bsum, NN, 4*NE);
  make_cursor_kernel<<<NSCAN_BLKS, 256, 0, stream>>>(row_ptr2, counts, cursor, sub_ptr);
  scatter_bucketed<<<NBUCK*EDGE_BLKS, 256, 0, stream>>>(edges, cursor, col2);

  convert_x_kernel<<<(NN*64 + 255)/256, 256, 0, stream>>>(x, xpad);

  const int gemmGX = (NN + 63)/64;   // 782

  for (int l = 0; l < 3; ++l) {
    const ushort* hin = (l == 0) ? xpad : hbuf;
    const int Kin = (l == 0) ? 23 : 64;
    convert_wb_kernel<<<(4*128*64 + 255)/256, 256, 0, stream>>>(W[l], WB, Kin);
    walwar_kernel<<<(16*64 + 255)/256, 256, 0, stream>>>(W[l], al[l], ar[l], wwb, Kin);
    elk_kernel<<<gemmGX, 256, 0, stream>>>(hin, wwb, elp, erp);
    gather_kernel<<<NN/4, 256, 0, stream>>>(hin, elp, erp, col2, row_ptr2, sub_ptr, agg);
    transform_kernel<<<gemmGX, 256, 0, stream>>>(agg, WB, b[l], hbuf, (l < 2) ? 1 : 0);
  }

  zero_floats<<<1, 64, 0, stream>>>(accum, 64);
  reduce_nodes<<<256, 256, 0, stream>>>(hbuf, accum);
  final_out_kernel<<<1, 64, 0, stream>>>(accum, (float*)d_out);
}

// Round 12
// 396.668 us; speedup vs baseline: 1.2532x; 1.1274x over previous
//
#include <hip/hip_runtime.h>

#define NN 50000
#define NE 250000
#define NSCAN_BLKS ((NN + 255)/256)
#define EDGE_BLKS ((4*NE + 255)/256)
#define NBUCK 4
#define BSZ ((NN + NBUCK - 1)/NBUCK)

typedef __attribute__((ext_vector_type(8))) short bf16x8;
typedef __attribute__((ext_vector_type(4))) float f32x4;

__device__ inline ushort f2bf(float f) {          // RNE float->bf16
  uint u = __float_as_uint(f);
  return (ushort)((u + 0x7fffu + ((u >> 16) & 1u)) >> 16);
}
__device__ inline float bf2f(ushort b) { return __uint_as_float(((uint)b) << 16); }

// ---------------- small utils ----------------
__global__ __launch_bounds__(256) void zero_ints(int* __restrict__ p, int n) {
  int i = blockIdx.x*256 + threadIdx.x;
  if (i < n) p[i] = 0;
}
__global__ __launch_bounds__(256) void zero_floats(float* __restrict__ p, int n) {
  int i = blockIdx.x*256 + threadIdx.x;
  if (i < n) p[i] = 0.f;
}

// ---------------- unified CSR build (dst-keyed, etype-ordered sub-rows) ----------------
__global__ __launch_bounds__(256) void count_kernel(const int* __restrict__ edges, int* __restrict__ counts) {
  int idx = blockIdx.x*256 + threadIdx.x;
  if (idx >= 4*NE) return;
  int t = idx / NE, e = idx - t*NE;
  int dst = edges[(size_t)t*2*NE + NE + e];
  atomicAdd(&counts[t*NN + dst], 1);
}

__global__ __launch_bounds__(256) void sumdeg_kernel(const int* __restrict__ counts, int* __restrict__ totdeg) {
  int v = blockIdx.x*256 + threadIdx.x;
  if (v < NN) totdeg[v] = counts[v] + counts[NN+v] + counts[2*NN+v] + counts[3*NN+v];
}

__global__ __launch_bounds__(256) void scan1_kernel(const int* __restrict__ in, int* __restrict__ out, int* __restrict__ bsum, int n) {
  __shared__ int sd[256];
  int i = blockIdx.x*256 + threadIdx.x;
  int v = (i < n) ? in[i] : 0;
  sd[threadIdx.x] = v;
  __syncthreads();
  for (int off = 1; off < 256; off <<= 1) {
    int add = (threadIdx.x >= off) ? sd[threadIdx.x - off] : 0;
    __syncthreads();
    sd[threadIdx.x] += add;
    __syncthreads();
  }
  if (i < n) out[i] = sd[threadIdx.x] - v;          // exclusive within block
  if (threadIdx.x == 255) bsum[blockIdx.x] = sd[255];
}

__global__ __launch_bounds__(1024) void scan2_kernel(int* __restrict__ bsum, int nb) {
  __shared__ int sd[1024];
  int i = threadIdx.x;
  int v = (i < nb) ? bsum[i] : 0;
  sd[i] = v;
  __syncthreads();
  for (int off = 1; off < 1024; off <<= 1) {
    int add = (i >= off) ? sd[i - off] : 0;
    __syncthreads();
    sd[i] += add;
    __syncthreads();
  }
  if (i < nb) bsum[i] = sd[i] - v;
}

__global__ __launch_bounds__(256) void scan3b_kernel(int* __restrict__ rp, const int* __restrict__ bsum, int n, int total) {
  int i = blockIdx.x*256 + threadIdx.x;
  if (i < n) rp[i] += bsum[blockIdx.x];
  if (i == 0) rp[n] = total;
}

__global__ __launch_bounds__(256) void make_cursor_kernel(const int* __restrict__ rp2, const int* __restrict__ counts,
                                                          int* __restrict__ cursor, int* __restrict__ sub_ptr) {
  int v = blockIdx.x*256 + threadIdx.x;
  if (v >= NN) return;
  int b = rp2[v];
  int s1 = b  + counts[v];
  int s2 = s1 + counts[NN+v];
  int s3 = s2 + counts[2*NN+v];
  cursor[v] = b; cursor[NN+v] = s1; cursor[2*NN+v] = s2; cursor[3*NN+v] = s3;
  sub_ptr[NN+v] = s1; sub_ptr[2*NN+v] = s2; sub_ptr[3*NN+v] = s3;
}

// dst-bucketed scatter: bucket epochs keep col2/cursor writes in a ~1.2 MB window.
__global__ __launch_bounds__(256) void scatter_bucketed(const int* __restrict__ edges, int* __restrict__ cursor,
                                                        int* __restrict__ col2) {
  const int b = blockIdx.x / EDGE_BLKS;
  const int idx = (blockIdx.x - b*EDGE_BLKS)*256 + threadIdx.x;
  if (idx >= 4*NE) return;
  const int t = idx / NE, e = idx - t*NE;
  const int dst = edges[(size_t)t*2*NE + NE + e];
  if (dst < b*BSZ || dst >= (b+1)*BSZ) return;
  const int src = edges[(size_t)t*2*NE + e];
  const int pos = atomicAdd(&cursor[t*NN + dst], 1);
  col2[pos] = src;
}

// ---------------- input converts ----------------
__global__ __launch_bounds__(256) void convert_x_kernel(const float* __restrict__ x, ushort* __restrict__ xpad) {
  int i = blockIdx.x*256 + threadIdx.x;     // over NN*64
  if (i >= NN*64) return;
  int k = i & 63, n = i >> 6;
  xpad[i] = (k < 23) ? f2bf(x[n*23 + k]) : (ushort)0;
}

// WB[t][c][k] = bf16(W[t][k][c]), k padded to 64 (c = h*64 + dim)
__global__ __launch_bounds__(256) void convert_wb_kernel(const float* __restrict__ W, ushort* __restrict__ WB, int Kin) {
  int i = blockIdx.x*256 + threadIdx.x;     // over 4*128*64
  if (i >= 4*128*64) return;
  int k = i & 63, c = (i >> 6) & 127, t = i >> 13;
  float w = (k < Kin) ? W[((size_t)t*Kin + k)*128 + c] : 0.f;
  WB[i] = f2bf(w);
}

// wwb[c][k], c=0..15: lr=c>>3, t=(c>>1)&3, h=c&1; val = (W_t[:,h-block] @ a_t,h)[k]
__global__ __launch_bounds__(256) void walwar_kernel(const float* __restrict__ W, const float* __restrict__ al,
                                                     const float* __restrict__ ar, ushort* __restrict__ wwb, int Kin) {
  int i = blockIdx.x*256 + threadIdx.x;     // over 16*64
  if (i >= 16*64) return;
  int c = i >> 6, k = i & 63;
  int lr = c >> 3, t = (c >> 1) & 3, h = c & 1;
  float v = 0.f;
  if (k < Kin) {
    const float* A = (lr ? ar : al) + t*128 + h*64;
    const float* wr = W + ((size_t)t*Kin + k)*128 + h*64;
    for (int d = 0; d < 64; ++d) v += wr[d]*A[d];
  }
  wwb[i] = f2bf(v);
}

// ---------------- elk: el/er = h @ wwb^T via one MFMA n-block ----------------
__global__ __launch_bounds__(256)
void elk_kernel(const ushort* __restrict__ hbf, const ushort* __restrict__ wwb,
                float* __restrict__ elp, float* __restrict__ erp)
{
  __shared__ ushort BS[16*64];    // 2 KB
  __shared__ float sC[16*66];     // padded stride 66 -> 2-way (free)
  const int tid = threadIdx.x;
  if (tid < 128) ((bf16x8*)BS)[tid] = ((const bf16x8*)wwb)[tid];
  __syncthreads();

  const int wv = tid >> 6, lane = tid & 63;
  const int mrow = lane & 15, kq = lane >> 4;
  const int anode = blockIdx.x*64 + wv*16 + mrow;

  const bf16x8 a0 = *(const bf16x8*)(hbf + (size_t)anode*64 + kq*8);
  const bf16x8 a1 = *(const bf16x8*)(hbf + (size_t)anode*64 + 32 + kq*8);
  const bf16x8 b0 = *(const bf16x8*)(BS + mrow*64 + kq*8);
  const bf16x8 b1 = *(const bf16x8*)(BS + mrow*64 + 32 + kq*8);

  f32x4 acc = (f32x4){0.f,0.f,0.f,0.f};
  acc = __builtin_amdgcn_mfma_f32_16x16x32_bf16(a0, b0, acc, 0, 0, 0);
  acc = __builtin_amdgcn_mfma_f32_16x16x32_bf16(a1, b1, acc, 0, 0, 0);

  #pragma unroll
  for (int r = 0; r < 4; ++r) sC[mrow*66 + wv*16 + kq*4 + r] = acc[r];
  __syncthreads();

  const int t = tid >> 6, n = tid & 63;
  const int node = blockIdx.x*64 + n;
  if (node < NN) {
    float2 e2 = make_float2(sC[(t*2+0)*66 + n], sC[(t*2+1)*66 + n]);
    float2 r2 = make_float2(sC[(8+t*2+0)*66 + n], sC[(8+t*2+1)*66 + n]);
    ((float2*)elp)[(size_t)t*NN + node] = e2;
    ((float2*)erp)[(size_t)t*NN + node] = r2;
  }
}

// ---------------- gather: wave per node, SPLIT-WAVE (half-wave per edge parity) ----------------
// Lanes 0-31 process even edges, 32-63 odd edges; within a half, lane j owns dims {2j,2j+1}
// (one dword of the h row). One wave iteration = 2 edges. Per-etype epilogue combines the
// halves via shfl_xor(32); head0 dwords written by lanes<32, head1 by lanes>=32 (NT stores).
__global__ __launch_bounds__(256)
void gather_kernel(const ushort* __restrict__ hbf, const float* __restrict__ elp,
                   const float* __restrict__ erp, const int* __restrict__ col2,
                   const int* __restrict__ row_ptr2, const int* __restrict__ sub_ptr,
                   ushort* __restrict__ agg)
{
  const int v = __builtin_amdgcn_readfirstlane(blockIdx.x*4 + (threadIdx.x >> 6));
  const int lane = threadIdx.x & 63;
  const int h2 = lane >> 5;            // edge parity of this half-wave
  const int j  = lane & 31;            // dim pair: dims 2j, 2j+1
  const uint* hb32 = (const uint*)hbf;
  uint* agg32 = (uint*)agg;

  const int b0 = row_ptr2[v];
  const int b4 = row_ptr2[v+1];
  const int s1 = sub_ptr[NN+v], s2 = sub_ptr[2*NN+v], s3 = sub_ptr[3*NN+v];
  const int bounds[5] = {b0, s1, s2, s3, b4};

  #pragma unroll
  for (int t = 0; t < 4; ++t) {
    const int lo = bounds[t], hi = bounds[t+1];
    float ox = 0.f, oy = 0.f;
    if (lo < hi) {
      const float2 er2 = ((const float2*)erp)[(size_t)t*NN + v];
      float sum0 = 0.f, sum1 = 0.f, tx0 = 0.f, ty0 = 0.f, tx1 = 0.f, ty1 = 0.f;
      #pragma unroll 2
      for (int q = lo + h2; q < hi; q += 2) {
        const int src = col2[q];                          // uniform per half
        const float2 e2 = ((const float2*)elp)[(size_t)t*NN + src];
        float u0 = e2.x + er2.x, u1 = e2.y + er2.y;
        u0 = (u0 > 0.f) ? u0 : 0.2f*u0;                   // leaky_relu 0.2
        u1 = (u1 > 0.f) ? u1 : 0.2f*u1;
        const float p0 = __expf(fminf(u0, 80.f));
        const float p1 = __expf(fminf(u1, 80.f));
        sum0 += p0; sum1 += p1;
        const uint w = hb32[(uint)src*32u + (uint)j];     // dims 2j,2j+1
        const float xv0 = __uint_as_float(w << 16);
        const float xv1 = __uint_as_float(w & 0xffff0000u);
        tx0 += p0*xv0; ty0 += p0*xv1;                     // head0
        tx1 += p1*xv0; ty1 += p1*xv1;                     // head1
      }
      sum0 += __shfl_xor(sum0, 32); sum1 += __shfl_xor(sum1, 32);
      tx0 += __shfl_xor(tx0, 32);   ty0 += __shfl_xor(ty0, 32);
      tx1 += __shfl_xor(tx1, 32);   ty1 += __shfl_xor(ty1, 32);
      const float i0 = __builtin_amdgcn_rcpf(sum0);
      const float i1 = __builtin_amdgcn_rcpf(sum1);
      ox = h2 ? tx1*i1 : tx0*i0;                          // my half writes its head
      oy = h2 ? ty1*i1 : ty0*i0;
    }
    const uint pk = (uint)f2bf(ox) | ((uint)f2bf(oy) << 16);
    __builtin_nontemporal_store(pk, &agg32[(size_t)(t*NN + v)*64 + h2*32 + j]);
  }
}

// ---------------- transform: h' = post(0.25*sum_t(agg_t @ W_t) + bmean) ----------------
// Block 256 = 4 waves x 16 nodes; N=128 (8 n-blocks: 0-3 head0, 4-7 head1); K=64.
// W staged in TWO 32KB stages; agg read via nontemporal loads (stream-once).
__global__ __launch_bounds__(256)
void transform_kernel(const ushort* __restrict__ agg, const ushort* __restrict__ WB,
                      const float* __restrict__ ball, ushort* __restrict__ hout, int post)
{
  __shared__ ushort WT[2*128*64];   // 32 KB, swizzled
  __shared__ float sb[128];
  const int tid = threadIdx.x;
  if (tid < 128) sb[tid] = 0.25f*(ball[tid] + ball[128+tid] + ball[256+tid] + ball[384+tid]);

  const int wv = tid >> 6, lane = tid & 63;
  const int mrow = lane & 15, kq = lane >> 4;
  const int node0 = blockIdx.x*64;
  const int anode = node0 + wv*16 + mrow;

  f32x4 acc[8];
  #pragma unroll
  for (int nb = 0; nb < 8; ++nb) acc[nb] = (f32x4){0.f,0.f,0.f,0.f};

  for (int tb = 0; tb < 4; tb += 2) {
    __syncthreads();                              // protect WT (and sb on first pass)
    for (int i = tid; i < 2048; i += 256) {       // 16B chunks: rows 0..255 = etypes tb,tb+1
      int row = i >> 3, jj = i & 7;
      bf16x8 val = ((const bf16x8*)WB)[tb*1024 + i];
      *(bf16x8*)((char*)WT + row*128 + ((jj ^ (row & 7))*16)) = val;
    }
    __syncthreads();
    #pragma unroll
    for (int t2 = 0; t2 < 2; ++t2) {
      const int t = tb + t2;
      const ushort* ar_ = agg + ((size_t)t*NN + anode)*128;
      const bf16x8 a00 = __builtin_nontemporal_load((const bf16x8*)(ar_ + kq*8));
      const bf16x8 a01 = __builtin_nontemporal_load((const bf16x8*)(ar_ + 32 + kq*8));
      const bf16x8 a10 = __builtin_nontemporal_load((const bf16x8*)(ar_ + 64 + kq*8));
      const bf16x8 a11 = __builtin_nontemporal_load((const bf16x8*)(ar_ + 96 + kq*8));
      #pragma unroll
      for (int nb = 0; nb < 8; ++nb) {
        const int row = t2*128 + nb*16 + mrow;
        const bf16x8 b0 = *(const bf16x8*)((const char*)WT + row*128 + ((kq       ^ (row&7))*16));
        const bf16x8 b1 = *(const bf16x8*)((const char*)WT + row*128 + (((4 + kq) ^ (row&7))*16));
        acc[nb] = __builtin_amdgcn_mfma_f32_16x16x32_bf16(nb < 4 ? a00 : a10, b0, acc[nb], 0, 0, 0);
        acc[nb] = __builtin_amdgcn_mfma_f32_16x16x32_bf16(nb < 4 ? a01 : a11, b1, acc[nb], 0, 0, 0);
      }
    }
  }

  const int noder = node0 + wv*16 + kq*4;
  #pragma unroll
  for (int nb = 0; nb < 4; ++nb) {
    const int d = nb*16 + mrow;
    const float bm0 = sb[d], bm1 = sb[64 + d];
    #pragma unroll
    for (int r = 0; r < 4; ++r) {
      if (noder + r < NN) {
        float h0 = 0.25f*acc[nb][r]   + bm0;
        float h1 = 0.25f*acc[nb+4][r] + bm1;
        float o;
        if (post) {
          h0 = fmaxf(h0, 0.f); h1 = fmaxf(h1, 0.f);
          o = 0.5f*(h0 + h1) / fmaxf(sqrtf(h0*h0 + h1*h1), 1e-12f);
        } else {
          o = 0.5f*(h0 + h1);
        }
        hout[(size_t)(noder + r)*64 + d] = f2bf(o);
      }
    }
  }
}

// ---------------- final mean over nodes (bf16 input) ----------------
__global__ __launch_bounds__(256) void reduce_nodes(const ushort* __restrict__ hn, float* __restrict__ accum) {
  __shared__ float sd[256];
  int d = threadIdx.x & 63, rg = threadIdx.x >> 6;
  float s = 0.f;
  for (int r = blockIdx.x*4 + rg; r < NN; r += gridDim.x*4) s += bf2f(hn[(size_t)r*64 + d]);
  sd[threadIdx.x] = s;
  __syncthreads();
  if (threadIdx.x < 64) {
    s = sd[threadIdx.x] + sd[threadIdx.x+64] + sd[threadIdx.x+128] + sd[threadIdx.x+192];
    atomicAdd(&accum[threadIdx.x], s);
  }
}
__global__ __launch_bounds__(64) void final_out_kernel(const float* __restrict__ accum, float* __restrict__ out) {
  int d = threadIdx.x;
  if (d < 64) out[d] = accum[d] * (1.0f/NN);
}

// ---------------- launch ----------------
extern "C" void kernel_launch(void* const* d_in, const int* in_sizes, int n_in,
                              void* d_out, int out_size, void* d_ws, size_t ws_size,
                              hipStream_t stream) {
  const float* x     = (const float*)d_in[0];
  const int*   edges = (const int*)d_in[1];
  const float* W[3]  = {(const float*)d_in[2], (const float*)d_in[6], (const float*)d_in[10]};
  const float* al[3] = {(const float*)d_in[3], (const float*)d_in[7], (const float*)d_in[11]};
  const float* ar[3] = {(const float*)d_in[4], (const float*)d_in[8], (const float*)d_in[12]};
  const float* b[3]  = {(const float*)d_in[5], (const float*)d_in[9], (const float*)d_in[13]};

  char* ws = (char*)d_ws;
  auto up = [](size_t x_) { return (x_ + 255) & ~(size_t)255; };

  const size_t szAgg  = ((size_t)4*NN + 64)*128*sizeof(ushort);  // 51.2 MB (+pad rows)
  const size_t szElp  = (size_t)4*NN*2*sizeof(float);            // 1.6 MB each
  const size_t szHB   = (size_t)(NN+64)*64*sizeof(ushort);       // 6.4 MB each
  const size_t szWB   = (size_t)4*128*64*sizeof(ushort);         // 64 KB
  const size_t szWWB  = (size_t)16*64*sizeof(ushort);            // 2 KB
  const size_t szCol  = (size_t)4*NE*sizeof(int);                // 4 MB
  const size_t szI4   = (size_t)4*NN*sizeof(int);
  const size_t szI1   = (size_t)(NN+1)*sizeof(int);

  size_t o = 0;
  ushort* agg    = (ushort*)(ws + o); o += up(szAgg);
  float*  elp    = (float*)(ws + o);  o += up(szElp);
  float*  erp    = (float*)(ws + o);  o += up(szElp);
  ushort* xpad   = (ushort*)(ws + o); o += up(szHB);
  ushort* hbuf   = (ushort*)(ws + o); o += up(szHB);
  ushort* WB     = (ushort*)(ws + o); o += up(szWB);
  ushort* wwb    = (ushort*)(ws + o); o += up(szWWB);
  float*  accum  = (float*)(ws + o);  o += up(256);
  int*    col2   = (int*)(ws + o);    o += up(szCol);
  int* row_ptr2  = (int*)(ws + o);    o += up(szI1);
  int* totdeg    = (int*)(ws + o);    o += up(szI1);
  int* cursor    = (int*)(ws + o);    o += up(szI4);
  int* counts    = (int*)(ws + o);    o += up(szI4);
  int* sub_ptr   = (int*)(ws + o);    o += up(szI4);
  int* bsum      = (int*)(ws + o);    o += up(4096);

  // ---- unified CSR build (once; shared by all layers) ----
  zero_ints<<<(4*NN + 255)/256, 256, 0, stream>>>(counts, 4*NN);
  count_kernel<<<EDGE_BLKS, 256, 0, stream>>>(edges, counts);
  sumdeg_kernel<<<NSCAN_BLKS, 256, 0, stream>>>(counts, totdeg);
  scan1_kernel<<<NSCAN_BLKS, 256, 0, stream>>>(totdeg, row_ptr2, bsum, NN);
  scan2_kernel<<<1, 1024, 0, stream>>>(bsum, NSCAN_BLKS);
  scan3b_kernel<<<NSCAN_BLKS, 256, 0, stream>>>(row_ptr2, bsum, NN, 4*NE);
  make_cursor_kernel<<<NSCAN_BLKS, 256, 0, stream>>>(row_ptr2, counts, cursor, sub_ptr);
  scatter_bucketed<<<NBUCK*EDGE_BLKS, 256, 0, stream>>>(edges, cursor, col2);

  convert_x_kernel<<<(NN*64 + 255)/256, 256, 0, stream>>>(x, xpad);

  const int gemmGX = (NN + 63)/64;   // 782

  for (int l = 0; l < 3; ++l) {
    const ushort* hin = (l == 0) ? xpad : hbuf;
    const int Kin = (l == 0) ? 23 : 64;
    convert_wb_kernel<<<(4*128*64 + 255)/256, 256, 0, stream>>>(W[l], WB, Kin);
    walwar_kernel<<<(16*64 + 255)/256, 256, 0, stream>>>(W[l], al[l], ar[l], wwb, Kin);
    elk_kernel<<<gemmGX, 256, 0, stream>>>(hin, wwb, elp, erp);
    gather_kernel<<<NN/4, 256, 0, stream>>>(hin, elp, erp, col2, row_ptr2, sub_ptr, agg);
    transform_kernel<<<gemmGX, 256, 0, stream>>>(agg, WB, b[l], hbuf, (l < 2) ? 1 : 0);
  }

  zero_floats<<<1, 64, 0, stream>>>(accum, 64);
  reduce_nodes<<<256, 256, 0, stream>>>(hbuf, accum);
  final_out_kernel<<<1, 64, 0, stream>>>(accum, (float*)d_out);
}